// Round 10
// baseline (306.563 us; speedup 1.0000x reference)
//
#include <hip/hip_runtime.h>

typedef _Float16 h2 __attribute__((ext_vector_type(2)));
typedef _Float16 h4 __attribute__((ext_vector_type(4)));
typedef _Float16 h8 __attribute__((ext_vector_type(8)));
typedef float    f4 __attribute__((ext_vector_type(4)));

#define TT 512
#define NB 512
#define II 32
#define HH 64
#define BT 16          // batch tile per block
#define LROW 72        // padded LDS row (f16 units)

static __device__ __forceinline__ float fexp2f(float x){ return __builtin_amdgcn_exp2f(x); }
static __device__ __forceinline__ float frcpf(float x){ return __builtin_amdgcn_rcpf(x); }
static __device__ __forceinline__ float sigf(float x){ return frcpf(1.0f + fexp2f(-1.442695040888963f*x)); }
static __device__ __forceinline__ float tanhf_fast(float x){ return 1.0f - 2.0f*frcpf(1.0f + fexp2f(2.885390081777926f*x)); }

struct H8S { h2 a,b,c,d; };
struct H4S { h2 a,b; };
static __device__ __forceinline__ h2 pkrtz(float a, float b){
  return __builtin_bit_cast(h2, __builtin_amdgcn_cvt_pkrtz(a, b));
}
static __device__ __forceinline__ h8 pack8(h2 a, h2 b, h2 c, h2 d){
  H8S s{a,b,c,d}; return __builtin_bit_cast(h8, s);
}
static __device__ __forceinline__ h8 cvt8(float4 a, float4 b){
  return pack8(pkrtz(a.x,a.y), pkrtz(a.z,a.w), pkrtz(b.x,b.y), pkrtz(b.z,b.w));
}
static __device__ __forceinline__ h8 ld8cvt(const float* p){
  return cvt8(((const float4*)p)[0], ((const float4*)p)[1]);
}
static __device__ __forceinline__ f4 mfma16(h8 a, h8 b, f4 c){
  return __builtin_amdgcn_mfma_f32_16x16x32_f16(a, b, c, 0, 0, 0);
}

// Raw barrier: drains LDS ops (correctness of the h exchange) but leaves
// global loads (x prefetch) IN FLIGHT across the barrier. __syncthreads()
// would emit s_waitcnt vmcnt(0) and serialize the HBM latency into every
// phase (R8/R9: ~900cy/phase stall, prefetch depth irrelevant).
static __device__ __forceinline__ void phase_barrier(){
  asm volatile("s_waitcnt lgkmcnt(0)" ::: "memory");
  __builtin_amdgcn_s_barrier();
  __builtin_amdgcn_sched_barrier(0);
  asm volatile("" ::: "memory");
}

// 32 blocks x 512 threads (8 waves). Waves 0-3: layer0; waves 4-7: layer1,
// software-pipelined one step behind (one barrier/phase).
__global__ __attribute__((amdgpu_flat_work_group_size(512,512)))
void gru2_pipe(
    const float* __restrict__ x,
    const float* __restrict__ Wih0, const float* __restrict__ Whh0,
    const float* __restrict__ bih0, const float* __restrict__ bhh0,
    const float* __restrict__ Wih1, const float* __restrict__ Whh1,
    const float* __restrict__ b_ih1, const float* __restrict__ b_hh1,
    const float* __restrict__ fcw, const float* __restrict__ fcb,
    float* __restrict__ out)
{
  const int tid  = threadIdx.x;
  const int w    = tid >> 6;        // wave 0..7
  const int lane = tid & 63;
  const int c    = lane & 15;       // batch within tile
  const int g    = lane >> 4;       // k-group / reg-row group
  const int wt   = w & 3;           // row-tile index within layer group
  const bool isL0 = (w < 4);
  const int b0   = blockIdx.x * BT;

  __shared__ _Float16 h0L[2][16*LROW];
  __shared__ _Float16 h1L[2][16*LROW];
  __shared__ float    fcred[256];

  for (int i = tid; i < 16*LROW; i += 512){
    h0L[0][i] = (_Float16)0; h0L[1][i] = (_Float16)0;
    h1L[0][i] = (_Float16)0; h1L[1][i] = (_Float16)0;
  }

  // ---- persistent A-frags: each wave loads only its layer's weights ----
  const int r0 = 16*wt + c, r1 = 64 + 16*wt + c, r2 = 128 + 16*wt + c;
  const int j0 = 16*wt + 4*g;          // units this lane owns

  h8 Ax[3];        // L0: x-part rows (r,z,ni), K=32
  h8 Ah[3][2];     // L0: h-part rows (r,z,nh), K=64
  h8 P0[3][2];     // L1: h0-part (Wih1) rows (r,z,ni)
  h8 P1[3][2];     // L1: h1-part (Whh1) rows (r,z,nh)
  f4 brv, bzv, biv, bhv;               // per-lane bias vectors (C-init)

  if (isL0) {
    Ax[0] = ld8cvt(Wih0 + r0*II + 8*g);
    Ax[1] = ld8cvt(Wih0 + r1*II + 8*g);
    Ax[2] = ld8cvt(Wih0 + r2*II + 8*g);
#pragma unroll
    for (int q = 0; q < 2; ++q){
      Ah[0][q] = ld8cvt(Whh0 + r0*HH + 32*q + 8*g);
      Ah[1][q] = ld8cvt(Whh0 + r1*HH + 32*q + 8*g);
      Ah[2][q] = ld8cvt(Whh0 + r2*HH + 32*q + 8*g);
    }
#pragma unroll
    for (int i = 0; i < 4; ++i){
      brv[i] = bih0[j0+i]     + bhh0[j0+i];
      bzv[i] = bih0[64+j0+i]  + bhh0[64+j0+i];
      biv[i] = bih0[128+j0+i];
      bhv[i] = bhh0[128+j0+i];
    }
  } else {
#pragma unroll
    for (int q = 0; q < 2; ++q){
      P0[0][q] = ld8cvt(Wih1 + r0*HH + 32*q + 8*g);
      P0[1][q] = ld8cvt(Wih1 + r1*HH + 32*q + 8*g);
      P0[2][q] = ld8cvt(Wih1 + r2*HH + 32*q + 8*g);
      P1[0][q] = ld8cvt(Whh1 + r0*HH + 32*q + 8*g);
      P1[1][q] = ld8cvt(Whh1 + r1*HH + 32*q + 8*g);
      P1[2][q] = ld8cvt(Whh1 + r2*HH + 32*q + 8*g);
    }
#pragma unroll
    for (int i = 0; i < 4; ++i){
      brv[i] = b_ih1[j0+i]     + b_hh1[j0+i];
      bzv[i] = b_ih1[64+j0+i]  + b_hh1[64+j0+i];
      biv[i] = b_ih1[128+j0+i];
      bhv[i] = b_hh1[128+j0+i];
    }
  }

  float hp[4] = {0.f,0.f,0.f,0.f};   // recurrent carry (L0: h0; L1: h1)

  // depth-2 x prefetch, RAW f32 (convert only at use). With the raw
  // barrier these stay in flight across phases: ~2 phases >= HBM latency.
  const float* xrow = x + (size_t)(b0+c)*TT*II + 8*g;
  float4 x0a, x0b, x1a, x1b;
  if (isL0) {
    x0a = ((const float4*)xrow)[0];       x0b = ((const float4*)xrow)[1];
    x1a = ((const float4*)(xrow+II))[0];  x1b = ((const float4*)(xrow+II))[1];
  }

  int buf = 0;
  __syncthreads();

  for (int p = 0; p <= TT; ++p){
    if (isL0) {
      if (p < TT) {
        const _Float16* h0r = &h0L[buf][c*LROW];
        h8 ba = *(const h8*)(h0r + 8*g);
        h8 bb = *(const h8*)(h0r + 32 + 8*g);
        h8 bx = cvt8(x0a, x0b);            // x[p]: landed >=2 phases ago
        f4 Cr = brv, Cz = bzv, Cni = biv, Cnh = bhv;
        Cr  = mfma16(Ax[0], bx, Cr);
        Cz  = mfma16(Ax[1], bx, Cz);
        Cni = mfma16(Ax[2], bx, Cni);
        Cr  = mfma16(Ah[0][0], ba, Cr);   Cr  = mfma16(Ah[0][1], bb, Cr);
        Cz  = mfma16(Ah[1][0], ba, Cz);   Cz  = mfma16(Ah[1][1], bb, Cz);
        Cnh = mfma16(Ah[2][0], ba, Cnh);  Cnh = mfma16(Ah[2][1], bb, Cnh);
        // shift prefetch window; issue load for x[p+2]
        x0a = x1a; x0b = x1b;
        {
          const float* pn = xrow + (size_t)((p+2 < TT) ? (p+2) : (TT-1))*II;
          x1a = ((const float4*)pn)[0];  x1b = ((const float4*)pn)[1];
        }
#pragma unroll
        for (int i = 0; i < 4; ++i){
          const float r  = sigf(Cr[i]);
          const float z  = sigf(Cz[i]);
          const float nn = tanhf_fast(Cni[i] + r*Cnh[i]);
          hp[i] = nn + z*(hp[i] - nn);
        }
        H4S s{ pkrtz(hp[0], hp[1]), pkrtz(hp[2], hp[3]) };
        *(h4*)(&h0L[buf^1][c*LROW + j0]) = __builtin_bit_cast(h4, s);
      }
    } else {
      if (p >= 1) {
        const _Float16* h0r = &h0L[buf][c*LROW];   // h0[p-1]
        const _Float16* h1r = &h1L[buf][c*LROW];   // h1[p-2]
        h8 a0 = *(const h8*)(h0r + 8*g);
        h8 a1 = *(const h8*)(h0r + 32 + 8*g);
        h8 v0 = *(const h8*)(h1r + 8*g);
        h8 v1 = *(const h8*)(h1r + 32 + 8*g);
        f4 Dr = brv, Dz = bzv, Dni = biv, Dnh = bhv;
        Dr  = mfma16(P0[0][0], a0, Dr);   Dr  = mfma16(P0[0][1], a1, Dr);
        Dr  = mfma16(P1[0][0], v0, Dr);   Dr  = mfma16(P1[0][1], v1, Dr);
        Dz  = mfma16(P0[1][0], a0, Dz);   Dz  = mfma16(P0[1][1], a1, Dz);
        Dz  = mfma16(P1[1][0], v0, Dz);   Dz  = mfma16(P1[1][1], v1, Dz);
        Dni = mfma16(P0[2][0], a0, Dni);  Dni = mfma16(P0[2][1], a1, Dni);
        Dnh = mfma16(P1[2][0], v0, Dnh);  Dnh = mfma16(P1[2][1], v1, Dnh);
#pragma unroll
        for (int i = 0; i < 4; ++i){
          const float r  = sigf(Dr[i]);
          const float z  = sigf(Dz[i]);
          const float nn = tanhf_fast(Dni[i] + r*Dnh[i]);
          hp[i] = nn + z*(hp[i] - nn);
        }
        H4S s{ pkrtz(hp[0], hp[1]), pkrtz(hp[2], hp[3]) };
        *(h4*)(&h1L[buf^1][c*LROW + j0]) = __builtin_bit_cast(h4, s);
      }
    }
    phase_barrier();
    buf ^= 1;
  }

  // ---- FC epilogue: L1 waves hold h1[TT-1] in hp ----
  if (!isL0) {
    float s = fcw[j0]*hp[0] + fcw[j0+1]*hp[1] + fcw[j0+2]*hp[2] + fcw[j0+3]*hp[3];
    fcred[(wt*4 + g)*16 + c] = s;
  }
  __syncthreads();
  if (tid < 16){
    float s = fcb[0];
#pragma unroll
    for (int q = 0; q < 16; ++q) s += fcred[q*16 + tid];
    out[b0 + tid] = s;
  }
}

extern "C" void kernel_launch(void* const* d_in, const int* in_sizes, int n_in,
                              void* d_out, int out_size, void* d_ws, size_t ws_size,
                              hipStream_t stream) {
  const float* x    = (const float*)d_in[0];
  const float* Wih0 = (const float*)d_in[1];
  const float* Whh0 = (const float*)d_in[2];
  const float* bih0 = (const float*)d_in[3];
  const float* bhh0 = (const float*)d_in[4];
  const float* Wih1 = (const float*)d_in[5];
  const float* Whh1 = (const float*)d_in[6];
  const float* bih1 = (const float*)d_in[7];
  const float* bhh1 = (const float*)d_in[8];
  const float* fcw  = (const float*)d_in[9];
  const float* fcb  = (const float*)d_in[10];
  float* out = (float*)d_out;

  gru2_pipe<<<dim3(NB/BT), dim3(512), 0, stream>>>(
      x, Wih0, Whh0, bih0, bhh0, Wih1, Whh1, bih1, bhh1, fcw, fcb, out);
}